// Round 9
// baseline (282.312 us; speedup 1.0000x reference)
//
#include <hip/hip_runtime.h>
#include <math.h>

#define BATCH 128
#define CIN 3
#define H 224
#define W 224
#define C1 16
#define HP 56
#define WP 56
#define C2 32
#define H2 28
#define W2 28

// ---------------------------------------------------------------------------
// Raw patch load for conv1: PURE loads, no dependent VALU — lets the next
// stage's loads stay in flight across this stage's FMAs (partial vmcnt wait).
// Boundary masks are applied at CONSUME time, not here.
// ---------------------------------------------------------------------------
__device__ __forceinline__ void c1_loadraw(const float* __restrict__ img,
                                           int rbase, int cbase,
                                           float4 f4[5], float lf[5])
{
#pragma unroll
    for (int r = 0; r < 5; ++r) {
        const int ih = max(rbase + r, 0);
        const float* rowp = img + ih * W;
        f4[r] = *(const float4*)(rowp + cbase);     // 16B-aligned
        lf[r] = rowp[max(cbase - 1, 0)];
    }
}

// ---------------------------------------------------------------------------
// conv1 (s2,p1) + stats + 2x2 pool(max,min), single pass, SW-PIPELINED.
// Thread = ONE pooled cell x 8 channels; grid (1568, 2) = 12544 waves.
// ci-loop: issue raw loads of ci+1, then mask+FMA ci (loads overlap compute).
// ---------------------------------------------------------------------------
__global__ __launch_bounds__(256) void conv1_fused_k(
    const float* __restrict__ x, const float* __restrict__ w1,
    const float* __restrict__ b1, float2* __restrict__ mm,
    float* __restrict__ s_sum, float* __restrict__ s_sq)
{
    __shared__ float red[4][8], redq[4][8];
    const int tid = threadIdx.x;
    const int t = blockIdx.x * 256 + tid;   // 0..401407
    const int c0 = blockIdx.y * 8;
    const int n = t / 3136;
    const int p = t % 3136;
    const int ph = p / WP, pw = p % WP;
    const int rbase = 4 * ph - 1;
    const int cbase = 4 * pw;
    const bool topok = ph > 0;
    const bool pwok  = pw > 0;

    float acc[8][4];
#pragma unroll
    for (int j = 0; j < 8; ++j) {
        const float bb = b1[c0 + j];
#pragma unroll
        for (int q = 0; q < 4; ++q) acc[j][q] = bb;
    }

    float4 rf4[2][5];
    float  rlf[2][5];
    c1_loadraw(x + (n * CIN + 0) * (H * W), rbase, cbase, rf4[0], rlf[0]);

#pragma unroll
    for (int ci = 0; ci < CIN; ++ci) {
        // prefetch next channel's raw patch (no consumer until next stage)
        if (ci + 1 < CIN)
            c1_loadraw(x + (n * CIN + ci + 1) * (H * W), rbase, cbase,
                       rf4[(ci + 1) & 1], rlf[(ci + 1) & 1]);
        // mask current raw patch at consume time
        float P[5][5];
#pragma unroll
        for (int r = 0; r < 5; ++r) {
            const float4 f4 = rf4[ci & 1][r];
            const bool rok = (r > 0) || topok;   // folds for r>0
            P[r][0] = (rok && pwok) ? rlf[ci & 1][r] : 0.0f;
            P[r][1] = rok ? f4.x : 0.0f;
            P[r][2] = rok ? f4.y : 0.0f;
            P[r][3] = rok ? f4.z : 0.0f;
            P[r][4] = rok ? f4.w : 0.0f;
        }
#pragma unroll
        for (int j = 0; j < 8; ++j) {
            const float* wc = w1 + ((c0 + j) * CIN + ci) * 9;  // uniform
#pragma unroll
            for (int kh = 0; kh < 3; ++kh) {
#pragma unroll
                for (int kw = 0; kw < 3; ++kw) {
                    const float wv = wc[kh * 3 + kw];
                    acc[j][0] += wv * P[kh][kw];
                    acc[j][1] += wv * P[kh][kw + 2];
                    acc[j][2] += wv * P[kh + 2][kw];
                    acc[j][3] += wv * P[kh + 2][kw + 2];
                }
            }
        }
    }

#pragma unroll
    for (int j = 0; j < 8; ++j) {
        const float a0 = acc[j][0], a1 = acc[j][1];
        const float a2 = acc[j][2], a3 = acc[j][3];
        mm[(n * C1 + c0 + j) * (HP * WP) + p] =
            make_float2(fmaxf(fmaxf(a0, a1), fmaxf(a2, a3)),
                        fminf(fminf(a0, a1), fminf(a2, a3)));
        float s = a0 + a1 + a2 + a3;
        float q = a0 * a0 + a1 * a1 + a2 * a2 + a3 * a3;
#pragma unroll
        for (int off = 32; off > 0; off >>= 1) {
            s += __shfl_xor(s, off);
            q += __shfl_xor(q, off);
        }
        if ((tid & 63) == 0) { red[tid >> 6][j] = s; redq[tid >> 6][j] = q; }
    }
    __syncthreads();
    if (tid < 8) {
        atomicAdd(&s_sum[c0 + tid],
                  red[0][tid] + red[1][tid] + red[2][tid] + red[3][tid]);
    } else if (tid < 16) {
        const int j = tid - 8;
        atomicAdd(&s_sq[c0 + j],
                  redq[0][j] + redq[1][j] + redq[2][j] + redq[3][j]);
    }
}

// ---------------------------------------------------------------------------
// Raw row loads for conv2 (pure loads; BN transform + masks at consume).
// ---------------------------------------------------------------------------
__device__ __forceinline__ void c2_loadraw(const float2* __restrict__ pl,
                                           int oh, int ow,
                                           float4 f4[3], float2 f2[3])
{
#pragma unroll
    for (int kh = 0; kh < 3; ++kh) {
        const int ih = max(2 * oh - 1 + kh, 0);
        const float2* rowp = pl + ih * WP;
        f4[kh] = *(const float4*)(rowp + 2 * ow);   // 2 (mx,mn) pairs, 16B
        f2[kh] = rowp[max(2 * ow - 1, 0)];
    }
}

// ---------------------------------------------------------------------------
// conv2 (s2,p1) + stats; BN1 finalize folded in; SW-PIPELINED over 16 ci.
// Thread = one output position x 8 channels. Grid (392, 4).
// ---------------------------------------------------------------------------
__global__ __launch_bounds__(256) void conv2_k(
    const float2* __restrict__ mm,
    const float* __restrict__ s1sum, const float* __restrict__ s1sq,
    const float* __restrict__ g1, const float* __restrict__ be1,
    const float* __restrict__ w2, const float* __restrict__ b2,
    float* __restrict__ y2,
    float* __restrict__ s_sum, float* __restrict__ s_sq)
{
    __shared__ float red[4][8], redq[4][8];
    const int tid = threadIdx.x;
    const int t = blockIdx.x * 256 + tid;   // 0..100351
    const int c0 = blockIdx.y * 8;
    const int n = t / 784;
    const int p = t % 784;
    const int oh = p / W2, ow = p % W2;
    const bool topok = oh > 0;
    const bool owok  = ow > 0;
    const float inv1 = 1.0f / (float)(BATCH * 112 * 112);

    float acc[8];
#pragma unroll
    for (int c = 0; c < 8; ++c) acc[c] = b2[c0 + c];

    float4 qf4[2][3];
    float2 qf2[2][3];
    c2_loadraw(mm + (n * C1 + 0) * (HP * WP), oh, ow, qf4[0], qf2[0]);

#pragma unroll
    for (int ci = 0; ci < C1; ++ci) {
        // prefetch next input channel's raw rows
        if (ci + 1 < C1)
            c2_loadraw(mm + (n * C1 + ci + 1) * (HP * WP), oh, ow,
                       qf4[(ci + 1) & 1], qf2[(ci + 1) & 1]);

        // BN1 params (uniform; scalar pipe)
        const float mean = s1sum[ci] * inv1;
        const float var  = s1sq[ci] * inv1 - mean * mean;
        const float s1 = g1[ci] * rsqrtf(var + 1e-5f);
        const float t1 = be1[ci] - mean * s1;

        // transform current raw rows: h1 = relu(max(s*mx+t, s*mn+t))
        float v[3][3];
#pragma unroll
        for (int kh = 0; kh < 3; ++kh) {
            const float4 f4 = qf4[ci & 1][kh];
            const float2 lp = qf2[ci & 1][kh];
            const bool rok = (kh > 0) || topok;   // folds for kh>0
            const float h0 = fmaxf(0.0f, fmaxf(s1 * lp.x + t1, s1 * lp.y + t1));
            const float h1 = fmaxf(0.0f, fmaxf(s1 * f4.x + t1, s1 * f4.y + t1));
            const float h2 = fmaxf(0.0f, fmaxf(s1 * f4.z + t1, s1 * f4.w + t1));
            v[kh][0] = (rok && owok) ? h0 : 0.0f;
            v[kh][1] = rok ? h1 : 0.0f;
            v[kh][2] = rok ? h2 : 0.0f;
        }
#pragma unroll
        for (int c = 0; c < 8; ++c) {
            const float* wc = w2 + ((c0 + c) * C1 + ci) * 9;   // uniform
            float a = acc[c];
            a += wc[0] * v[0][0]; a += wc[1] * v[0][1]; a += wc[2] * v[0][2];
            a += wc[3] * v[1][0]; a += wc[4] * v[1][1]; a += wc[5] * v[1][2];
            a += wc[6] * v[2][0]; a += wc[7] * v[2][1]; a += wc[8] * v[2][2];
            acc[c] = a;
        }
    }

#pragma unroll
    for (int c = 0; c < 8; ++c) {
        const float a = acc[c];
        y2[(n * C2 + c0 + c) * (H2 * W2) + p] = a;
        float s = a, q = a * a;
#pragma unroll
        for (int off = 32; off > 0; off >>= 1) {
            s += __shfl_xor(s, off);
            q += __shfl_xor(q, off);
        }
        if ((tid & 63) == 0) { red[tid >> 6][c] = s; redq[tid >> 6][c] = q; }
    }
    __syncthreads();
    if (tid < 8) {
        atomicAdd(&s_sum[c0 + tid],
                  red[0][tid] + red[1][tid] + red[2][tid] + red[3][tid]);
    } else if (tid < 16) {
        const int c = tid - 8;
        atomicAdd(&s_sq[c0 + c],
                  redq[0][c] + redq[1][c] + redq[2][c] + redq[3][c]);
    }
}

// ---------------------------------------------------------------------------
// head fused: BN2 finalize + ReLU + avgpool + FC + cos, one block per image.
// ---------------------------------------------------------------------------
__global__ __launch_bounds__(256) void head_fused_k(
    const float* __restrict__ y2,
    const float* __restrict__ s2sum, const float* __restrict__ s2sq,
    const float* __restrict__ g2, const float* __restrict__ be2,
    const float* __restrict__ fcw, const float* __restrict__ fcb,
    float* __restrict__ out)
{
    __shared__ float feat[C2];
    const int n = blockIdx.x;
    const int tid = threadIdx.x;
    const int wave = tid >> 6, lane = tid & 63;
    const float inv2 = 1.0f / (float)(BATCH * H2 * W2);
#pragma unroll
    for (int k = 0; k < 8; ++k) {
        const int c = wave * 8 + k;
        const float mean = s2sum[c] * inv2;
        const float var  = s2sq[c] * inv2 - mean * mean;
        const float s = g2[c] * rsqrtf(var + 1e-5f);
        const float t = be2[c] - mean * s;
        const float4* yp = (const float4*)(y2 + (n * C2 + c) * (H2 * W2));
        float a = 0.0f;
        for (int i = lane; i < 196; i += 64) {       // 196 quads = 784
            const float4 v = yp[i];
            a += fmaxf(0.0f, s * v.x + t) + fmaxf(0.0f, s * v.y + t)
               + fmaxf(0.0f, s * v.z + t) + fmaxf(0.0f, s * v.w + t);
        }
#pragma unroll
        for (int off = 32; off > 0; off >>= 1) a += __shfl_xor(a, off);
        if (lane == 0) feat[c] = a * (1.0f / (H2 * W2));
    }
    __syncthreads();
    if (tid == 0) {
        float logit = fcb[0];
#pragma unroll
        for (int c = 0; c < C2; ++c) logit += feat[c] * fcw[c];
        const float pc = cosf(logit);
        out[2 * n]     = pc;
        out[2 * n + 1] = 1.0f - pc;
    }
}

extern "C" void kernel_launch(void* const* d_in, const int* in_sizes, int n_in,
                              void* d_out, int out_size, void* d_ws, size_t ws_size,
                              hipStream_t stream) {
    const float* x   = (const float*)d_in[0];
    const float* w1  = (const float*)d_in[1];
    const float* b1  = (const float*)d_in[2];
    const float* g1  = (const float*)d_in[3];
    const float* be1 = (const float*)d_in[4];
    const float* w2  = (const float*)d_in[5];
    const float* b2  = (const float*)d_in[6];
    const float* g2  = (const float*)d_in[7];
    const float* be2 = (const float*)d_in[8];
    const float* fcw = (const float*)d_in[9];
    const float* fcb = (const float*)d_in[10];
    float* out = (float*)d_out;

    float* ws = (float*)d_ws;
    float2* mm = (float2*)ws;                              // 6,422,528 float2
    float* y2 = ws + (size_t)2 * BATCH * C1 * HP * WP;     // 3,211,264 floats
    float* stats = y2 + (size_t)BATCH * C2 * H2 * W2;
    float* s1sum = stats;          // 16
    float* s1sq  = stats + 16;     // 16
    float* s2sum = stats + 32;     // 32
    float* s2sq  = stats + 64;     // 32
    // ws use ~64.3 MB (proven safe)

    hipMemsetAsync(stats, 0, 96 * sizeof(float), stream);

    conv1_fused_k<<<dim3(1568, 2), 256, 0, stream>>>(x, w1, b1, mm, s1sum, s1sq);
    conv2_k<<<dim3(392, 4), 256, 0, stream>>>(mm, s1sum, s1sq, g1, be1,
                                              w2, b2, y2, s2sum, s2sq);
    head_fused_k<<<BATCH, 256, 0, stream>>>(y2, s2sum, s2sq, g2, be2,
                                            fcw, fcb, out);
}

// Round 10
// 249.550 us; speedup vs baseline: 1.1313x; 1.1313x over previous
//
#include <hip/hip_runtime.h>
#include <math.h>

#define BATCH 128
#define CIN 3
#define H 224
#define W 224
#define C1 16
#define HP 56
#define WP 56
#define C2 32
#define H2 28
#define W2 28

// ---------------------------------------------------------------------------
// conv1 (s2,p1) + stats + 2x2 pool(max,min), SINGLE PASS (R8-proven, 55us).
// Thread = 2 vertically-adjacent pooled cells x 8 channels. Grid (784, 2).
// ---------------------------------------------------------------------------
__global__ __launch_bounds__(256) void conv1_fused_k(
    const float* __restrict__ x, const float* __restrict__ w1,
    const float* __restrict__ b1, float2* __restrict__ mm,
    float* __restrict__ s_sum, float* __restrict__ s_sq)
{
    __shared__ float red[4][8], redq[4][8];
    const int tid = threadIdx.x;
    const int t = blockIdx.x * 256 + tid;   // 0..200703
    const int c0 = blockIdx.y * 8;
    const int n = t / 1568;
    const int r = t % 1568;
    const int phh = r / 56;                 // 0..27
    const int pw  = r % 56;
    const int rbase = 8 * phh - 1;
    const int cbase = 4 * pw;
    const bool topok = phh > 0;
    const bool pwok  = pw > 0;

    float accA[8][4], accB[8][4];
#pragma unroll
    for (int j = 0; j < 8; ++j) {
        const float bb = b1[c0 + j];
#pragma unroll
        for (int q = 0; q < 4; ++q) { accA[j][q] = bb; accB[j][q] = bb; }
    }

#pragma unroll
    for (int ci = 0; ci < CIN; ++ci) {
        const float* img = x + (n * CIN + ci) * (H * W);
        float p[9][5];
#pragma unroll
        for (int l = 0; l < 9; ++l) {
            const int ih = max(rbase + l, 0);
            const float* rowp = img + ih * W;
            const float4 f4 = *(const float4*)(rowp + cbase);
            const float lf = rowp[max(cbase - 1, 0)];
            const bool rok = (l > 0) || topok;   // folds for l>0
            p[l][0] = (rok && pwok) ? lf : 0.0f;
            p[l][1] = rok ? f4.x : 0.0f;
            p[l][2] = rok ? f4.y : 0.0f;
            p[l][3] = rok ? f4.z : 0.0f;
            p[l][4] = rok ? f4.w : 0.0f;
        }
#pragma unroll
        for (int j = 0; j < 8; ++j) {
            const float* wc = w1 + ((c0 + j) * CIN + ci) * 9;  // uniform
#pragma unroll
            for (int kh = 0; kh < 3; ++kh) {
#pragma unroll
                for (int kw = 0; kw < 3; ++kw) {
                    const float wv = wc[kh * 3 + kw];
                    accA[j][0] += wv * p[kh][kw];
                    accA[j][1] += wv * p[kh][kw + 2];
                    accA[j][2] += wv * p[kh + 2][kw];
                    accA[j][3] += wv * p[kh + 2][kw + 2];
                    accB[j][0] += wv * p[4 + kh][kw];
                    accB[j][1] += wv * p[4 + kh][kw + 2];
                    accB[j][2] += wv * p[6 + kh][kw];
                    accB[j][3] += wv * p[6 + kh][kw + 2];
                }
            }
        }
    }

#pragma unroll
    for (int j = 0; j < 8; ++j) {
        const int o = (n * C1 + c0 + j) * (HP * WP) + (2 * phh) * WP + pw;
        const float a0 = accA[j][0], a1 = accA[j][1], a2 = accA[j][2], a3 = accA[j][3];
        const float b0 = accB[j][0], b1v = accB[j][1], b2v = accB[j][2], b3 = accB[j][3];
        mm[o] = make_float2(fmaxf(fmaxf(a0, a1), fmaxf(a2, a3)),
                            fminf(fminf(a0, a1), fminf(a2, a3)));
        mm[o + WP] = make_float2(fmaxf(fmaxf(b0, b1v), fmaxf(b2v, b3)),
                                 fminf(fminf(b0, b1v), fminf(b2v, b3)));
        float s = a0 + a1 + a2 + a3 + b0 + b1v + b2v + b3;
        float q = a0 * a0 + a1 * a1 + a2 * a2 + a3 * a3
                + b0 * b0 + b1v * b1v + b2v * b2v + b3 * b3;
#pragma unroll
        for (int off = 32; off > 0; off >>= 1) {
            s += __shfl_xor(s, off);
            q += __shfl_xor(q, off);
        }
        if ((tid & 63) == 0) { red[tid >> 6][j] = s; redq[tid >> 6][j] = q; }
    }
    __syncthreads();
    if (tid < 8) {
        atomicAdd(&s_sum[c0 + tid],
                  red[0][tid] + red[1][tid] + red[2][tid] + red[3][tid]);
    } else if (tid < 16) {
        const int j = tid - 8;
        atomicAdd(&s_sq[c0 + j],
                  redq[0][j] + redq[1][j] + redq[2][j] + redq[3][j]);
    }
}

// ---------------------------------------------------------------------------
// conv2 (s2,p1) + stats; BN1 folded. EXPERIMENT: 16 output channels per
// thread — same 6 loads/ci as R6/R8, double the FMA (ratio 12 -> 24) to
// amortize L2/L3 load latency. 128-thread blocks, grid (784, 2) keeps the
// proven 1568-block dispatch (6.1 blocks/CU). VGPR ~50 (<=64, max w/SIMD).
// ---------------------------------------------------------------------------
__global__ __launch_bounds__(128) void conv2_k(
    const float2* __restrict__ mm,
    const float* __restrict__ s1sum, const float* __restrict__ s1sq,
    const float* __restrict__ g1, const float* __restrict__ be1,
    const float* __restrict__ w2, const float* __restrict__ b2,
    float* __restrict__ y2,
    float* __restrict__ s_sum, float* __restrict__ s_sq)
{
    __shared__ float red[2][16], redq[2][16];
    const int tid = threadIdx.x;
    const int t = blockIdx.x * 128 + tid;   // 0..100351
    const int c0 = blockIdx.y * 16;
    const int n = t / 784;
    const int p = t % 784;
    const int oh = p / W2, ow = p % W2;
    const bool topok = oh > 0;
    const bool owok  = ow > 0;
    const float inv1 = 1.0f / (float)(BATCH * 112 * 112);

    float acc[16];
#pragma unroll
    for (int c = 0; c < 16; ++c) acc[c] = b2[c0 + c];

#pragma unroll 2
    for (int ci = 0; ci < C1; ++ci) {
        const float mean = s1sum[ci] * inv1;
        const float var  = s1sq[ci] * inv1 - mean * mean;
        const float s1 = g1[ci] * rsqrtf(var + 1e-5f);
        const float t1 = be1[ci] - mean * s1;

        const float2* pl = mm + (n * C1 + ci) * (HP * WP);
        float v[3][3];
#pragma unroll
        for (int kh = 0; kh < 3; ++kh) {
            const int ih = max(2 * oh - 1 + kh, 0);
            const float2* rowp = pl + ih * WP;
            const float4 f4 = *(const float4*)(rowp + 2 * ow);
            const float2 lp = rowp[max(2 * ow - 1, 0)];
            const bool rok = (kh > 0) || topok;   // folds for kh>0
            const float h0 = fmaxf(0.0f, fmaxf(s1 * lp.x + t1, s1 * lp.y + t1));
            const float h1 = fmaxf(0.0f, fmaxf(s1 * f4.x + t1, s1 * f4.y + t1));
            const float h2 = fmaxf(0.0f, fmaxf(s1 * f4.z + t1, s1 * f4.w + t1));
            v[kh][0] = (rok && owok) ? h0 : 0.0f;
            v[kh][1] = rok ? h1 : 0.0f;
            v[kh][2] = rok ? h2 : 0.0f;
        }
#pragma unroll
        for (int c = 0; c < 16; ++c) {
            const float* wc = w2 + ((c0 + c) * C1 + ci) * 9;   // uniform
            float a = acc[c];
            a += wc[0] * v[0][0]; a += wc[1] * v[0][1]; a += wc[2] * v[0][2];
            a += wc[3] * v[1][0]; a += wc[4] * v[1][1]; a += wc[5] * v[1][2];
            a += wc[6] * v[2][0]; a += wc[7] * v[2][1]; a += wc[8] * v[2][2];
            acc[c] = a;
        }
    }

#pragma unroll
    for (int c = 0; c < 16; ++c) {
        const float a = acc[c];
        y2[(n * C2 + c0 + c) * (H2 * W2) + p] = a;
        float s = a, q = a * a;
#pragma unroll
        for (int off = 32; off > 0; off >>= 1) {
            s += __shfl_xor(s, off);
            q += __shfl_xor(q, off);
        }
        if ((tid & 63) == 0) { red[tid >> 6][c] = s; redq[tid >> 6][c] = q; }
    }
    __syncthreads();
    if (tid < 16) {
        atomicAdd(&s_sum[c0 + tid], red[0][tid] + red[1][tid]);
    } else if (tid < 32) {
        const int c = tid - 16;
        atomicAdd(&s_sq[c0 + c], redq[0][c] + redq[1][c]);
    }
}

// ---------------------------------------------------------------------------
// head fused: BN2 finalize + ReLU + avgpool + FC + cos, one block per image.
// (R8-proven.)
// ---------------------------------------------------------------------------
__global__ __launch_bounds__(256) void head_fused_k(
    const float* __restrict__ y2,
    const float* __restrict__ s2sum, const float* __restrict__ s2sq,
    const float* __restrict__ g2, const float* __restrict__ be2,
    const float* __restrict__ fcw, const float* __restrict__ fcb,
    float* __restrict__ out)
{
    __shared__ float feat[C2];
    const int n = blockIdx.x;
    const int tid = threadIdx.x;
    const int wave = tid >> 6, lane = tid & 63;
    const float inv2 = 1.0f / (float)(BATCH * H2 * W2);
#pragma unroll
    for (int k = 0; k < 8; ++k) {
        const int c = wave * 8 + k;
        const float mean = s2sum[c] * inv2;
        const float var  = s2sq[c] * inv2 - mean * mean;
        const float s = g2[c] * rsqrtf(var + 1e-5f);
        const float t = be2[c] - mean * s;
        const float4* yp = (const float4*)(y2 + (n * C2 + c) * (H2 * W2));
        float a = 0.0f;
        for (int i = lane; i < 196; i += 64) {       // 196 quads = 784
            const float4 v = yp[i];
            a += fmaxf(0.0f, s * v.x + t) + fmaxf(0.0f, s * v.y + t)
               + fmaxf(0.0f, s * v.z + t) + fmaxf(0.0f, s * v.w + t);
        }
#pragma unroll
        for (int off = 32; off > 0; off >>= 1) a += __shfl_xor(a, off);
        if (lane == 0) feat[c] = a * (1.0f / (H2 * W2));
    }
    __syncthreads();
    if (tid == 0) {
        float logit = fcb[0];
#pragma unroll
        for (int c = 0; c < C2; ++c) logit += feat[c] * fcw[c];
        const float pc = cosf(logit);
        out[2 * n]     = pc;
        out[2 * n + 1] = 1.0f - pc;
    }
}

extern "C" void kernel_launch(void* const* d_in, const int* in_sizes, int n_in,
                              void* d_out, int out_size, void* d_ws, size_t ws_size,
                              hipStream_t stream) {
    const float* x   = (const float*)d_in[0];
    const float* w1  = (const float*)d_in[1];
    const float* b1  = (const float*)d_in[2];
    const float* g1  = (const float*)d_in[3];
    const float* be1 = (const float*)d_in[4];
    const float* w2  = (const float*)d_in[5];
    const float* b2  = (const float*)d_in[6];
    const float* g2  = (const float*)d_in[7];
    const float* be2 = (const float*)d_in[8];
    const float* fcw = (const float*)d_in[9];
    const float* fcb = (const float*)d_in[10];
    float* out = (float*)d_out;

    float* ws = (float*)d_ws;
    float2* mm = (float2*)ws;                              // 6,422,528 float2
    float* y2 = ws + (size_t)2 * BATCH * C1 * HP * WP;     // 3,211,264 floats
    float* stats = y2 + (size_t)BATCH * C2 * H2 * W2;
    float* s1sum = stats;          // 16
    float* s1sq  = stats + 16;     // 16
    float* s2sum = stats + 32;     // 32
    float* s2sq  = stats + 64;     // 32
    // ws use ~64.3 MB (proven safe)

    hipMemsetAsync(stats, 0, 96 * sizeof(float), stream);

    conv1_fused_k<<<dim3(784, 2), 256, 0, stream>>>(x, w1, b1, mm, s1sum, s1sq);
    conv2_k<<<dim3(784, 2), 128, 0, stream>>>(mm, s1sum, s1sq, g1, be1,
                                              w2, b2, y2, s2sum, s2sq);
    head_fused_k<<<BATCH, 256, 0, stream>>>(y2, s2sum, s2sq, g2, be2,
                                            fcw, fcb, out);
}

// Round 11
// 219.880 us; speedup vs baseline: 1.2839x; 1.1349x over previous
//
#include <hip/hip_runtime.h>
#include <math.h>

#define BATCH 128
#define CIN 3
#define H 224
#define W 224
#define C1 16
#define HP 56
#define WP 56
#define C2 32
#define H2 28
#define W2 28

typedef float v2f __attribute__((ext_vector_type(2)));

// ---------------------------------------------------------------------------
// conv1 (s2,p1) + stats + 2x2 pool(max,min), SINGLE PASS.
// R8 structure (2 vertical pooled cells x 8 channels, grid (784,2)) with
// PACKED-FP32 accumulation: cells Aq/Bq share the same weight and use patch
// rows (r, r+4) -> v2f pairs rp[r][s] = {P[r][s], P[r+4][s]}; acc += w2*rp
// contracts to v_pk_fma_f32 (ffp-contract=fast), halving FMA issue count.
// Accumulator register cost unchanged (8j x 4 v2f = 64 regs).
// ---------------------------------------------------------------------------
__global__ __launch_bounds__(256) void conv1_fused_k(
    const float* __restrict__ x, const float* __restrict__ w1,
    const float* __restrict__ b1, float2* __restrict__ mm,
    float* __restrict__ s_sum, float* __restrict__ s_sq)
{
    __shared__ float red[4][8], redq[4][8];
    const int tid = threadIdx.x;
    const int t = blockIdx.x * 256 + tid;   // 0..200703
    const int c0 = blockIdx.y * 8;
    const int n = t / 1568;
    const int r = t % 1568;
    const int phh = r / 56;                 // 0..27
    const int pw  = r % 56;
    const int rbase = 8 * phh - 1;
    const int cbase = 4 * pw;
    const bool topok = phh > 0;
    const bool pwok  = pw > 0;

    // accq[j][q] = (cell Aq, cell Bq) packed
    v2f accq[8][4];
#pragma unroll
    for (int j = 0; j < 8; ++j) {
        const float bb = b1[c0 + j];
#pragma unroll
        for (int q = 0; q < 4; ++q) { accq[j][q].x = bb; accq[j][q].y = bb; }
    }

#pragma unroll
    for (int ci = 0; ci < CIN; ++ci) {
        const float* img = x + (n * CIN + ci) * (H * W);
        float P[9][5];
#pragma unroll
        for (int l = 0; l < 9; ++l) {
            const int ih = max(rbase + l, 0);
            const float* rowp = img + ih * W;
            const float4 f4 = *(const float4*)(rowp + cbase);
            const float lf = rowp[max(cbase - 1, 0)];
            const bool rok = (l > 0) || topok;   // folds for l>0
            P[l][0] = (rok && pwok) ? lf : 0.0f;
            P[l][1] = rok ? f4.x : 0.0f;
            P[l][2] = rok ? f4.y : 0.0f;
            P[l][3] = rok ? f4.z : 0.0f;
            P[l][4] = rok ? f4.w : 0.0f;
        }
        // row-pairs (r, r+4): cell A uses rows 0..4, cell B rows 4..8
        v2f rp[5][5];
#pragma unroll
        for (int rr = 0; rr < 5; ++rr)
#pragma unroll
            for (int s = 0; s < 5; ++s) { rp[rr][s].x = P[rr][s]; rp[rr][s].y = P[rr + 4][s]; }

#pragma unroll
        for (int j = 0; j < 8; ++j) {
            const float* wc = w1 + ((c0 + j) * CIN + ci) * 9;  // uniform
#pragma unroll
            for (int kh = 0; kh < 3; ++kh) {
#pragma unroll
                for (int kw = 0; kw < 3; ++kw) {
                    const float wv = wc[kh * 3 + kw];
                    v2f w2; w2.x = wv; w2.y = wv;
                    accq[j][0] += w2 * rp[kh][kw];
                    accq[j][1] += w2 * rp[kh][kw + 2];
                    accq[j][2] += w2 * rp[kh + 2][kw];
                    accq[j][3] += w2 * rp[kh + 2][kw + 2];
                }
            }
        }
    }

#pragma unroll
    for (int j = 0; j < 8; ++j) {
        const int o = (n * C1 + c0 + j) * (HP * WP) + (2 * phh) * WP + pw;
        const float a0 = accq[j][0].x, a1 = accq[j][1].x;
        const float a2 = accq[j][2].x, a3 = accq[j][3].x;
        const float b0 = accq[j][0].y, b1v = accq[j][1].y;
        const float b2v = accq[j][2].y, b3 = accq[j][3].y;
        mm[o] = make_float2(fmaxf(fmaxf(a0, a1), fmaxf(a2, a3)),
                            fminf(fminf(a0, a1), fminf(a2, a3)));
        mm[o + WP] = make_float2(fmaxf(fmaxf(b0, b1v), fmaxf(b2v, b3)),
                                 fminf(fminf(b0, b1v), fminf(b2v, b3)));
        float s = a0 + a1 + a2 + a3 + b0 + b1v + b2v + b3;
        float q = a0 * a0 + a1 * a1 + a2 * a2 + a3 * a3
                + b0 * b0 + b1v * b1v + b2v * b2v + b3 * b3;
#pragma unroll
        for (int off = 32; off > 0; off >>= 1) {
            s += __shfl_xor(s, off);
            q += __shfl_xor(q, off);
        }
        if ((tid & 63) == 0) { red[tid >> 6][j] = s; redq[tid >> 6][j] = q; }
    }
    __syncthreads();
    if (tid < 8) {
        atomicAdd(&s_sum[c0 + tid],
                  red[0][tid] + red[1][tid] + red[2][tid] + red[3][tid]);
    } else if (tid < 16) {
        const int j = tid - 8;
        atomicAdd(&s_sq[c0 + j],
                  redq[0][j] + redq[1][j] + redq[2][j] + redq[3][j]);
    }
}

// ---------------------------------------------------------------------------
// conv2 (s2,p1) + stats; BN1 finalize folded in (R8-proven, VERBATIM).
// Thread = ONE output position x 8 channels. Grid (392, 4).
// ---------------------------------------------------------------------------
__global__ __launch_bounds__(256) void conv2_k(
    const float2* __restrict__ mm,
    const float* __restrict__ s1sum, const float* __restrict__ s1sq,
    const float* __restrict__ g1, const float* __restrict__ be1,
    const float* __restrict__ w2, const float* __restrict__ b2,
    float* __restrict__ y2,
    float* __restrict__ s_sum, float* __restrict__ s_sq)
{
    __shared__ float red[4][8], redq[4][8];
    const int tid = threadIdx.x;
    const int t = blockIdx.x * 256 + tid;   // 0..100351
    const int c0 = blockIdx.y * 8;
    const int n = t / 784;
    const int p = t % 784;
    const int oh = p / W2, ow = p % W2;
    const bool topok = oh > 0;
    const bool owok  = ow > 0;
    const float inv1 = 1.0f / (float)(BATCH * 112 * 112);

    float acc[8];
#pragma unroll
    for (int c = 0; c < 8; ++c) acc[c] = b2[c0 + c];

#pragma unroll 2
    for (int ci = 0; ci < C1; ++ci) {
        const float mean = s1sum[ci] * inv1;
        const float var  = s1sq[ci] * inv1 - mean * mean;
        const float s1 = g1[ci] * rsqrtf(var + 1e-5f);
        const float t1 = be1[ci] - mean * s1;

        const float2* pl = mm + (n * C1 + ci) * (HP * WP);
        float v[3][3];
#pragma unroll
        for (int kh = 0; kh < 3; ++kh) {
            const int ih = max(2 * oh - 1 + kh, 0);
            const float2* rowp = pl + ih * WP;
            const float4 f4 = *(const float4*)(rowp + 2 * ow);
            const float2 lp = rowp[max(2 * ow - 1, 0)];
            const bool rok = (kh > 0) || topok;   // folds for kh>0
            const float h0 = fmaxf(0.0f, fmaxf(s1 * lp.x + t1, s1 * lp.y + t1));
            const float h1 = fmaxf(0.0f, fmaxf(s1 * f4.x + t1, s1 * f4.y + t1));
            const float h2 = fmaxf(0.0f, fmaxf(s1 * f4.z + t1, s1 * f4.w + t1));
            v[kh][0] = (rok && owok) ? h0 : 0.0f;
            v[kh][1] = rok ? h1 : 0.0f;
            v[kh][2] = rok ? h2 : 0.0f;
        }
#pragma unroll
        for (int c = 0; c < 8; ++c) {
            const float* wc = w2 + ((c0 + c) * C1 + ci) * 9;   // uniform
            float a = acc[c];
            a += wc[0] * v[0][0]; a += wc[1] * v[0][1]; a += wc[2] * v[0][2];
            a += wc[3] * v[1][0]; a += wc[4] * v[1][1]; a += wc[5] * v[1][2];
            a += wc[6] * v[2][0]; a += wc[7] * v[2][1]; a += wc[8] * v[2][2];
            acc[c] = a;
        }
    }

#pragma unroll
    for (int c = 0; c < 8; ++c) {
        const float a = acc[c];
        y2[(n * C2 + c0 + c) * (H2 * W2) + p] = a;
        float s = a, q = a * a;
#pragma unroll
        for (int off = 32; off > 0; off >>= 1) {
            s += __shfl_xor(s, off);
            q += __shfl_xor(q, off);
        }
        if ((tid & 63) == 0) { red[tid >> 6][c] = s; redq[tid >> 6][c] = q; }
    }
    __syncthreads();
    if (tid < 8) {
        atomicAdd(&s_sum[c0 + tid],
                  red[0][tid] + red[1][tid] + red[2][tid] + red[3][tid]);
    } else if (tid < 16) {
        const int c = tid - 8;
        atomicAdd(&s_sq[c0 + c],
                  redq[0][c] + redq[1][c] + redq[2][c] + redq[3][c]);
    }
}

// ---------------------------------------------------------------------------
// head fused: BN2 finalize + ReLU + avgpool + FC + cos, one block per image.
// (R8-proven, VERBATIM.)
// ---------------------------------------------------------------------------
__global__ __launch_bounds__(256) void head_fused_k(
    const float* __restrict__ y2,
    const float* __restrict__ s2sum, const float* __restrict__ s2sq,
    const float* __restrict__ g2, const float* __restrict__ be2,
    const float* __restrict__ fcw, const float* __restrict__ fcb,
    float* __restrict__ out)
{
    __shared__ float feat[C2];
    const int n = blockIdx.x;
    const int tid = threadIdx.x;
    const int wave = tid >> 6, lane = tid & 63;
    const float inv2 = 1.0f / (float)(BATCH * H2 * W2);
#pragma unroll
    for (int k = 0; k < 8; ++k) {
        const int c = wave * 8 + k;
        const float mean = s2sum[c] * inv2;
        const float var  = s2sq[c] * inv2 - mean * mean;
        const float s = g2[c] * rsqrtf(var + 1e-5f);
        const float t = be2[c] - mean * s;
        const float4* yp = (const float4*)(y2 + (n * C2 + c) * (H2 * W2));
        float a = 0.0f;
        for (int i = lane; i < 196; i += 64) {       // 196 quads = 784
            const float4 v = yp[i];
            a += fmaxf(0.0f, s * v.x + t) + fmaxf(0.0f, s * v.y + t)
               + fmaxf(0.0f, s * v.z + t) + fmaxf(0.0f, s * v.w + t);
        }
#pragma unroll
        for (int off = 32; off > 0; off >>= 1) a += __shfl_xor(a, off);
        if (lane == 0) feat[c] = a * (1.0f / (H2 * W2));
    }
    __syncthreads();
    if (tid == 0) {
        float logit = fcb[0];
#pragma unroll
        for (int c = 0; c < C2; ++c) logit += feat[c] * fcw[c];
        const float pc = cosf(logit);
        out[2 * n]     = pc;
        out[2 * n + 1] = 1.0f - pc;
    }
}

extern "C" void kernel_launch(void* const* d_in, const int* in_sizes, int n_in,
                              void* d_out, int out_size, void* d_ws, size_t ws_size,
                              hipStream_t stream) {
    const float* x   = (const float*)d_in[0];
    const float* w1  = (const float*)d_in[1];
    const float* b1  = (const float*)d_in[2];
    const float* g1  = (const float*)d_in[3];
    const float* be1 = (const float*)d_in[4];
    const float* w2  = (const float*)d_in[5];
    const float* b2  = (const float*)d_in[6];
    const float* g2  = (const float*)d_in[7];
    const float* be2 = (const float*)d_in[8];
    const float* fcw = (const float*)d_in[9];
    const float* fcb = (const float*)d_in[10];
    float* out = (float*)d_out;

    float* ws = (float*)d_ws;
    float2* mm = (float2*)ws;                              // 6,422,528 float2
    float* y2 = ws + (size_t)2 * BATCH * C1 * HP * WP;     // 3,211,264 floats
    float* stats = y2 + (size_t)BATCH * C2 * H2 * W2;
    float* s1sum = stats;          // 16
    float* s1sq  = stats + 16;     // 16
    float* s2sum = stats + 32;     // 32
    float* s2sq  = stats + 64;     // 32
    // ws use ~64.3 MB (proven safe)

    hipMemsetAsync(stats, 0, 96 * sizeof(float), stream);

    conv1_fused_k<<<dim3(784, 2), 256, 0, stream>>>(x, w1, b1, mm, s1sum, s1sq);
    conv2_k<<<dim3(392, 4), 256, 0, stream>>>(mm, s1sum, s1sq, g1, be1,
                                              w2, b2, y2, s2sum, s2sq);
    head_fused_k<<<BATCH, 256, 0, stream>>>(y2, s2sum, s2sq, g2, be2,
                                            fcw, fcb, out);
}